// Round 1
// baseline (606.153 us; speedup 1.0000x reference)
//
#include <hip/hip_runtime.h>

#define B_ 8
#define C_ 512
#define N_ 1024
#define GROUPS_ 32
#define CPG_ 16        // C / GROUPS
#define NH_ 8
#define HD_ 64

// ---------------------------------------------------------------------------
// GroupNorm: one block per (batch, group). Reduce 16x1024 elems, normalize.
// ---------------------------------------------------------------------------
__global__ __launch_bounds__(256) void gn_kernel(const float* __restrict__ x,
                                                 const float* __restrict__ gw,
                                                 const float* __restrict__ gb,
                                                 float* __restrict__ xn) {
  const int bg = blockIdx.x;
  const int b = bg / GROUPS_, g = bg % GROUPS_;
  const float* xp = x + ((size_t)b * C_ + (size_t)g * CPG_) * N_;
  float* xo = xn + ((size_t)b * C_ + (size_t)g * CPG_) * N_;
  const int tid = threadIdx.x;
  const int total = CPG_ * N_;  // 16384

  float s = 0.f, ss = 0.f;
  for (int i = tid * 4; i < total; i += 1024) {
    const float4 v = *reinterpret_cast<const float4*>(xp + i);
    s += v.x + v.y + v.z + v.w;
    ss += v.x * v.x + v.y * v.y + v.z * v.z + v.w * v.w;
  }
#pragma unroll
  for (int off = 32; off > 0; off >>= 1) {
    s += __shfl_down(s, off);
    ss += __shfl_down(ss, off);
  }
  __shared__ float red[8];
  __shared__ float stat[2];
  if ((tid & 63) == 0) { red[tid >> 6] = s; red[4 + (tid >> 6)] = ss; }
  __syncthreads();
  if (tid == 0) {
    s = red[0] + red[1] + red[2] + red[3];
    ss = red[4] + red[5] + red[6] + red[7];
    const float inv = 1.0f / (float)total;
    const float mu = s * inv;
    const float var = ss * inv - mu * mu;
    stat[0] = mu;
    stat[1] = rsqrtf(var + 1e-5f);
  }
  __syncthreads();
  const float mu = stat[0], rstd = stat[1];
  for (int i = tid * 4; i < total; i += 1024) {
    const int c = i >> 10;  // i / N_
    const float w = gw[g * CPG_ + c] * rstd;
    const float bb = gb[g * CPG_ + c] - mu * w;
    float4 v = *reinterpret_cast<const float4*>(xp + i);
    v.x = v.x * w + bb;
    v.y = v.y * w + bb;
    v.z = v.z * w + bb;
    v.w = v.w * w + bb;
    *reinterpret_cast<float4*>(xo + i) = v;
  }
}

// ---------------------------------------------------------------------------
// Batched GEMM: Y[b] = Wm (MxK) * X[b] (KxN_) [+ bias + res].  64x64 tile,
// K-step 16, 256 threads, 4x4 accumulators per thread. fp32 vector FMA.
// ---------------------------------------------------------------------------
__global__ __launch_bounds__(256) void gemm_kernel(const float* __restrict__ Wm,
                                                   const float* __restrict__ X,
                                                   float* __restrict__ Y,
                                                   const float* __restrict__ bias,
                                                   const float* __restrict__ res,
                                                   int M, int K) {
  const int nb = blockIdx.x * 64;
  const int mb = blockIdx.y * 64;
  const int b = blockIdx.z;
  const float* Xb = X + (size_t)b * K * N_;
  float* Yb = Y + (size_t)b * M * N_;

  __shared__ float As[16][68];  // As[k][m]
  __shared__ float Bs[16][68];  // Bs[k][n]

  const int tid = threadIdx.x;
  const int tx = tid & 15, ty = tid >> 4;

  float acc[4][4] = {};

  for (int k0 = 0; k0 < K; k0 += 16) {
    // A tile: 64(m) x 16(k), each thread one float4 along k, store transposed
    {
      const int m = tid >> 2;
      const int kk = (tid & 3) * 4;
      const float4 a =
          *reinterpret_cast<const float4*>(&Wm[(size_t)(mb + m) * K + k0 + kk]);
      As[kk + 0][m] = a.x;
      As[kk + 1][m] = a.y;
      As[kk + 2][m] = a.z;
      As[kk + 3][m] = a.w;
    }
    // B tile: 16(k) x 64(n), float4 along n
    {
      const int kk = tid >> 4;
      const int n = (tid & 15) * 4;
      *reinterpret_cast<float4*>(&Bs[kk][n]) =
          *reinterpret_cast<const float4*>(&Xb[(size_t)(k0 + kk) * N_ + nb + n]);
    }
    __syncthreads();
#pragma unroll
    for (int kk = 0; kk < 16; ++kk) {
      const float4 av = *reinterpret_cast<const float4*>(&As[kk][ty * 4]);
      const float4 bv = *reinterpret_cast<const float4*>(&Bs[kk][tx * 4]);
      const float a4[4] = {av.x, av.y, av.z, av.w};
      const float b4[4] = {bv.x, bv.y, bv.z, bv.w};
#pragma unroll
      for (int i = 0; i < 4; ++i)
#pragma unroll
        for (int j = 0; j < 4; ++j) acc[i][j] += a4[i] * b4[j];
    }
    __syncthreads();
  }

#pragma unroll
  for (int i = 0; i < 4; ++i) {
    const int m = mb + ty * 4 + i;
    const size_t off = (size_t)m * N_ + nb + tx * 4;
    float4 o = make_float4(acc[i][0], acc[i][1], acc[i][2], acc[i][3]);
    if (bias) {
      const float bv = bias[m];
      o.x += bv; o.y += bv; o.z += bv; o.w += bv;
    }
    if (res) {
      const float4 r =
          *reinterpret_cast<const float4*>(&res[(size_t)b * M * N_ + off]);
      o.x += r.x; o.y += r.y; o.z += r.z; o.w += r.w;
    }
    *reinterpret_cast<float4*>(&Yb[off]) = o;
  }
}

// ---------------------------------------------------------------------------
// Flash-style attention, fp32. One block per (head-batch, 64-query tile).
// qkv layout: (B, 1536, N_) == (B*NH_, 3*HD_, N_); q rows 0..63, k 64..127,
// v 128..191 within each head's 192-row band.
// ---------------------------------------------------------------------------
__global__ __launch_bounds__(256) void attn_kernel(const float* __restrict__ qkv,
                                                   float* __restrict__ h) {
  const int qt = blockIdx.x;  // 0..15
  const int bh = blockIdx.y;  // 0..63
  const int b = bh >> 3, head = bh & 7;
  const int qb = qt * 64;
  const float* base = qkv + ((size_t)b * (3 * C_) + (size_t)head * (3 * HD_)) * N_;
  const float* qp = base;
  const float* kp = base + (size_t)HD_ * N_;
  const float* vp = base + (size_t)(2 * HD_) * N_;

  __shared__ float Qs[64][68];   // Qs[c][t], scaled; reused for O staging
  __shared__ float Ks[64][68];   // Ks[c][s]; reused as Pst[s][t]
  __shared__ float Vts[64][68];  // Vts[s][c]

  const int tid = threadIdx.x;
  const int tx = tid & 15, ty = tid >> 4;

  // load Q tile, fold total softmax scale (1/8) into Q
  for (int it = 0; it < 4; ++it) {
    const int c = (tid >> 4) + it * 16;
    const int t0 = (tid & 15) * 4;
    float4 q = *reinterpret_cast<const float4*>(&qp[(size_t)c * N_ + qb + t0]);
    q.x *= 0.125f; q.y *= 0.125f; q.z *= 0.125f; q.w *= 0.125f;
    *reinterpret_cast<float4*>(&Qs[c][t0]) = q;
  }

  float m_run[4], l_run[4], oacc[4][4];
#pragma unroll
  for (int i = 0; i < 4; ++i) {
    m_run[i] = -1e30f;
    l_run[i] = 0.f;
#pragma unroll
    for (int j = 0; j < 4; ++j) oacc[i][j] = 0.f;
  }

  for (int sb = 0; sb < N_; sb += 64) {
    __syncthreads();  // prev iteration's reads of Ks/Vts (and Q store) done
    for (int it = 0; it < 4; ++it) {
      const int c = (tid >> 4) + it * 16;
      const int s0 = (tid & 15) * 4;
      *reinterpret_cast<float4*>(&Ks[c][s0]) =
          *reinterpret_cast<const float4*>(&kp[(size_t)c * N_ + sb + s0]);
      const float4 v =
          *reinterpret_cast<const float4*>(&vp[(size_t)c * N_ + sb + s0]);
      Vts[s0 + 0][c] = v.x;
      Vts[s0 + 1][c] = v.y;
      Vts[s0 + 2][c] = v.z;
      Vts[s0 + 3][c] = v.w;
    }
    __syncthreads();

    // S tile = Q^T K : rows t = ty*4+i, cols s = tx*4+j
    float sacc[4][4] = {};
#pragma unroll
    for (int c = 0; c < 64; ++c) {
      const float4 av = *reinterpret_cast<const float4*>(&Qs[c][ty * 4]);
      const float4 bv = *reinterpret_cast<const float4*>(&Ks[c][tx * 4]);
      const float a4[4] = {av.x, av.y, av.z, av.w};
      const float b4[4] = {bv.x, bv.y, bv.z, bv.w};
#pragma unroll
      for (int i = 0; i < 4; ++i)
#pragma unroll
        for (int j = 0; j < 4; ++j) sacc[i][j] += a4[i] * b4[j];
    }

    // online softmax over this 64-wide tile
    float alpha[4], psum[4];
#pragma unroll
    for (int i = 0; i < 4; ++i) {
      float mm = fmaxf(fmaxf(sacc[i][0], sacc[i][1]),
                       fmaxf(sacc[i][2], sacc[i][3]));
      mm = fmaxf(mm, __shfl_xor(mm, 1));
      mm = fmaxf(mm, __shfl_xor(mm, 2));
      mm = fmaxf(mm, __shfl_xor(mm, 4));
      mm = fmaxf(mm, __shfl_xor(mm, 8));
      const float mn = fmaxf(m_run[i], mm);
      alpha[i] = __expf(m_run[i] - mn);
      m_run[i] = mn;
      float ps = 0.f;
#pragma unroll
      for (int j = 0; j < 4; ++j) {
        sacc[i][j] = __expf(sacc[i][j] - mn);
        ps += sacc[i][j];
      }
      ps += __shfl_xor(ps, 1);
      ps += __shfl_xor(ps, 2);
      ps += __shfl_xor(ps, 4);
      ps += __shfl_xor(ps, 8);
      psum[i] = ps;
    }

    __syncthreads();  // everyone done reading Ks -> overwrite with P^T
#pragma unroll
    for (int i = 0; i < 4; ++i)
#pragma unroll
      for (int j = 0; j < 4; ++j) Ks[tx * 4 + j][ty * 4 + i] = sacc[i][j];

#pragma unroll
    for (int i = 0; i < 4; ++i) {
      l_run[i] = l_run[i] * alpha[i] + psum[i];
#pragma unroll
      for (int j = 0; j < 4; ++j) oacc[i][j] *= alpha[i];
    }
    __syncthreads();

    // O += P * V^T : rows t = ty*4+i, cols c = tx*4+j
#pragma unroll
    for (int s = 0; s < 64; ++s) {
      const float4 av = *reinterpret_cast<const float4*>(&Ks[s][ty * 4]);
      const float4 bv = *reinterpret_cast<const float4*>(&Vts[s][tx * 4]);
      const float a4[4] = {av.x, av.y, av.z, av.w};
      const float b4[4] = {bv.x, bv.y, bv.z, bv.w};
#pragma unroll
      for (int i = 0; i < 4; ++i)
#pragma unroll
        for (int j = 0; j < 4; ++j) oacc[i][j] += a4[i] * b4[j];
    }
  }

  // normalize, stage O (reuse Qs as Os[c][t]), write coalesced
  __syncthreads();
#pragma unroll
  for (int i = 0; i < 4; ++i) {
    const float inv = 1.0f / l_run[i];
#pragma unroll
    for (int j = 0; j < 4; ++j) Qs[tx * 4 + j][ty * 4 + i] = oacc[i][j] * inv;
  }
  __syncthreads();
  float* hb = h + ((size_t)b * C_ + (size_t)head * HD_) * N_;
  for (int it = 0; it < 4; ++it) {
    const int c = (tid >> 4) + it * 16;
    const int t0 = (tid & 15) * 4;
    *reinterpret_cast<float4*>(&hb[(size_t)c * N_ + qb + t0]) =
        *reinterpret_cast<const float4*>(&Qs[c][t0]);
  }
}

// ---------------------------------------------------------------------------
extern "C" void kernel_launch(void* const* d_in, const int* in_sizes, int n_in,
                              void* d_out, int out_size, void* d_ws,
                              size_t ws_size, hipStream_t stream) {
  const float* x = (const float*)d_in[0];
  const float* gn_w = (const float*)d_in[1];
  const float* gn_b = (const float*)d_in[2];
  const float* qkv_w = (const float*)d_in[3];
  const float* proj_w = (const float*)d_in[4];
  const float* proj_b = (const float*)d_in[5];
  float* out = (float*)d_out;

  char* ws = (char*)d_ws;
  float* xn = (float*)ws;                                   // 16 MiB
  float* qkv = (float*)(ws + (size_t)16 * 1024 * 1024);     // 48 MiB
  float* hbuf = (float*)(ws + (size_t)64 * 1024 * 1024);    // 16 MiB

  gn_kernel<<<dim3(B_ * GROUPS_), 256, 0, stream>>>(x, gn_w, gn_b, xn);
  gemm_kernel<<<dim3(N_ / 64, (3 * C_) / 64, B_), 256, 0, stream>>>(
      qkv_w, xn, qkv, nullptr, nullptr, 3 * C_, C_);
  attn_kernel<<<dim3(N_ / 64, B_ * NH_), 256, 0, stream>>>(qkv, hbuf);
  gemm_kernel<<<dim3(N_ / 64, C_ / 64, B_), 256, 0, stream>>>(
      proj_w, hbuf, out, proj_b, x, C_, C_);
}

// Round 2
// 209.160 us; speedup vs baseline: 2.8980x; 2.8980x over previous
//
#include <hip/hip_runtime.h>

#define B_ 8
#define C_ 512
#define N_ 1024
#define GROUPS_ 32
#define CPG_ 16
#define NH_ 8
#define HD_ 64

typedef _Float16 half8 __attribute__((ext_vector_type(8)));
typedef float f32x4 __attribute__((ext_vector_type(4)));

// ---------------------------------------------------------------------------
// fp32 -> fp16 elementwise convert (weights)
// ---------------------------------------------------------------------------
__global__ __launch_bounds__(256) void cvt_kernel(const float* __restrict__ in,
                                                  _Float16* __restrict__ out,
                                                  int n) {
  const int i = (blockIdx.x * 256 + threadIdx.x) * 4;
  if (i < n) {
    const float4 v = *reinterpret_cast<const float4*>(&in[i]);
    _Float16 h[4] = {(_Float16)v.x, (_Float16)v.y, (_Float16)v.z, (_Float16)v.w};
    *reinterpret_cast<uint2*>(&out[i]) = *reinterpret_cast<uint2*>(&h[0]);
  }
}

// ---------------------------------------------------------------------------
// GroupNorm: block per (b,g). fp32 stats, write TRANSPOSED fp16 xnT[b][n][c].
// ---------------------------------------------------------------------------
__global__ __launch_bounds__(256) void gn_kernel(const float* __restrict__ x,
                                                 const float* __restrict__ gw,
                                                 const float* __restrict__ gb,
                                                 _Float16* __restrict__ xnT) {
  const int bg = blockIdx.x;
  const int b = bg / GROUPS_, g = bg % GROUPS_;
  const float* xp = x + ((size_t)b * C_ + (size_t)g * CPG_) * N_;
  const int tid = threadIdx.x;
  const int total = CPG_ * N_;  // 16384

  float s = 0.f, ss = 0.f;
  for (int i = tid * 4; i < total; i += 1024) {
    const float4 v = *reinterpret_cast<const float4*>(xp + i);
    s += v.x + v.y + v.z + v.w;
    ss += v.x * v.x + v.y * v.y + v.z * v.z + v.w * v.w;
  }
#pragma unroll
  for (int off = 32; off > 0; off >>= 1) {
    s += __shfl_down(s, off);
    ss += __shfl_down(ss, off);
  }
  __shared__ float red[8];
  __shared__ float stat[2];
  if ((tid & 63) == 0) { red[tid >> 6] = s; red[4 + (tid >> 6)] = ss; }
  __syncthreads();
  if (tid == 0) {
    s = red[0] + red[1] + red[2] + red[3];
    ss = red[4] + red[5] + red[6] + red[7];
    const float inv = 1.0f / (float)total;
    const float mu = s * inv;
    const float var = ss * inv - mu * mu;
    stat[0] = mu;
    stat[1] = rsqrtf(var + 1e-5f);
  }
  __syncthreads();
  __shared__ float wsh[CPG_], bsh[CPG_];
  if (tid < CPG_) {
    const float w = gw[g * CPG_ + tid] * stat[1];
    wsh[tid] = w;
    bsh[tid] = gb[g * CPG_ + tid] - stat[0] * w;
  }
  __syncthreads();
#pragma unroll
  for (int it = 0; it < 4; ++it) {
    const int n = it * 256 + tid;
    _Float16 h[CPG_];
#pragma unroll
    for (int c = 0; c < CPG_; ++c)
      h[c] = (_Float16)(xp[c * N_ + n] * wsh[c] + bsh[c]);
    _Float16* dst = &xnT[((size_t)b * N_ + n) * C_ + g * CPG_];
    *reinterpret_cast<uint4*>(dst) = *reinterpret_cast<uint4*>(&h[0]);
    *reinterpret_cast<uint4*>(dst + 8) = *reinterpret_cast<uint4*>(&h[8]);
  }
}

// ---------------------------------------------------------------------------
// NT-GEMM via MFMA fp16: D[ar][bc] = sum_k A[ar][k] * B[bc][k]
// A: RAxK row-major, B: RBxK row-major (both fp16, K-contig).
// Tile 128x128, BK=32, 4 waves (2x2 of 64x64). fp32 accum.
// OUT_HALF: write fp16 D. EPI: fp32 D + bias[ar] + resid.
// ---------------------------------------------------------------------------
template <bool OUT_HALF, bool EPI>
__global__ __launch_bounds__(256) void gemm_tn(
    const _Float16* __restrict__ A, long strideAb,
    const _Float16* __restrict__ Bm, long strideBb,
    void* __restrict__ D, long strideDb, int ldd, int K,
    const float* __restrict__ bias, const float* __restrict__ resid,
    long strideRb) {
  const int bc0 = blockIdx.x * 128;
  const int ar0 = blockIdx.y * 128;
  const int b = blockIdx.z;
  const _Float16* Ab = A + (size_t)b * strideAb;
  const _Float16* Bb = Bm + (size_t)b * strideBb;

  __shared__ _Float16 As[128][40];  // +8 pad: 80B rows -> 2-way banks max
  __shared__ _Float16 Bs[128][40];

  const int tid = threadIdx.x;
  const int lane = tid & 63;
  const int wid = tid >> 6;
  const int war = (wid >> 1) * 64;
  const int wbc = (wid & 1) * 64;
  const int lg = lane >> 4;   // 0..3
  const int lr = lane & 15;   // 0..15

  const int srow = tid >> 1;
  const int skoff = (tid & 1) * 16;

  f32x4 acc[4][4] = {};

  for (int k0 = 0; k0 < K; k0 += 32) {
    __syncthreads();
    const float4 av0 = *reinterpret_cast<const float4*>(
        &Ab[(size_t)(ar0 + srow) * K + k0 + skoff]);
    const float4 av1 = *reinterpret_cast<const float4*>(
        &Ab[(size_t)(ar0 + srow) * K + k0 + skoff + 8]);
    const float4 bv0 = *reinterpret_cast<const float4*>(
        &Bb[(size_t)(bc0 + srow) * K + k0 + skoff]);
    const float4 bv1 = *reinterpret_cast<const float4*>(
        &Bb[(size_t)(bc0 + srow) * K + k0 + skoff + 8]);
    *reinterpret_cast<float4*>(&As[srow][skoff]) = av0;
    *reinterpret_cast<float4*>(&As[srow][skoff + 8]) = av1;
    *reinterpret_cast<float4*>(&Bs[srow][skoff]) = bv0;
    *reinterpret_cast<float4*>(&Bs[srow][skoff + 8]) = bv1;
    __syncthreads();

    half8 af[4], bf[4];
#pragma unroll
    for (int i = 0; i < 4; ++i)
      af[i] = *reinterpret_cast<const half8*>(&As[war + i * 16 + lr][lg * 8]);
#pragma unroll
    for (int j = 0; j < 4; ++j)
      bf[j] = *reinterpret_cast<const half8*>(&Bs[wbc + j * 16 + lr][lg * 8]);
#pragma unroll
    for (int i = 0; i < 4; ++i)
#pragma unroll
      for (int j = 0; j < 4; ++j)
        acc[i][j] = __builtin_amdgcn_mfma_f32_16x16x32_f16(af[i], bf[j],
                                                           acc[i][j], 0, 0, 0);
  }

  if (OUT_HALF) {
    _Float16* Dp = (_Float16*)D + (size_t)b * strideDb;
#pragma unroll
    for (int i = 0; i < 4; ++i)
#pragma unroll
      for (int r = 0; r < 4; ++r) {
        const int row = ar0 + war + i * 16 + lg * 4 + r;
#pragma unroll
        for (int j = 0; j < 4; ++j) {
          const int col = bc0 + wbc + j * 16 + lr;
          Dp[(size_t)row * ldd + col] = (_Float16)acc[i][j][r];
        }
      }
  }
  if (EPI) {
    float* Dp = (float*)D + (size_t)b * strideDb;
    const float* Rp = resid + (size_t)b * strideRb;
#pragma unroll
    for (int i = 0; i < 4; ++i)
#pragma unroll
      for (int r = 0; r < 4; ++r) {
        const int row = ar0 + war + i * 16 + lg * 4 + r;
        const float bv = bias[row];
#pragma unroll
        for (int j = 0; j < 4; ++j) {
          const int col = bc0 + wbc + j * 16 + lr;
          const size_t off = (size_t)row * ldd + col;
          Dp[off] = acc[i][j][r] + bv + Rp[off];
        }
      }
  }
}

// ---------------------------------------------------------------------------
// Flash attention via MFMA fp16. Block per (64-query tile, b*head).
// qkvT[b][n][m]: per head h: q cols h*192..+63, k +64, v +128.
// Per wave: 16-query stripe. Online softmax in fp32 registers.
// Output hT[b][n][head*64+c] fp16.
// ---------------------------------------------------------------------------
__global__ __launch_bounds__(256) void attn_mfma(const _Float16* __restrict__ qkvT,
                                                 _Float16* __restrict__ hT) {
  const int qt = blockIdx.x;
  const int bh = blockIdx.y;
  const int b = bh >> 3, head = bh & 7;
  const int qb = qt * 64;
  const size_t base = (size_t)b * N_ * 1536 + head * 192;

  __shared__ _Float16 Qs[64][72];  // [t][c], 144B rows
  __shared__ _Float16 Ks[64][72];  // [s][c]
  __shared__ _Float16 Vs[64][72];  // [c][s]  (transposed at staging)
  __shared__ _Float16 Ps[64][72];  // [t][s]

  const int tid = threadIdx.x;
  const int lane = tid & 63;
  const int wid = tid >> 6;
  const int lg = lane >> 4, lr = lane & 15;
  const int tw = wid * 16;         // wave's query-stripe base
  const int ss = tid >> 2;         // staging row 0..63
  const int sc = (tid & 3) * 16;   // staging col offset

  // stage Q (once)
  {
    const _Float16* qp = &qkvT[base + (size_t)(qb + ss) * 1536 + sc];
    *reinterpret_cast<float4*>(&Qs[ss][sc]) =
        *reinterpret_cast<const float4*>(qp);
    *reinterpret_cast<float4*>(&Qs[ss][sc + 8]) =
        *reinterpret_cast<const float4*>(qp + 8);
  }

  f32x4 oacc[4] = {};
  float m_run[4], l_run[4];
#pragma unroll
  for (int r = 0; r < 4; ++r) { m_run[r] = -1e30f; l_run[r] = 0.f; }

  for (int sb = 0; sb < N_; sb += 64) {
    __syncthreads();  // prev iter done with Ks/Vs (also covers Q staging)
    {
      const _Float16* kp = &qkvT[base + 64 + (size_t)(sb + ss) * 1536 + sc];
      *reinterpret_cast<float4*>(&Ks[ss][sc]) =
          *reinterpret_cast<const float4*>(kp);
      *reinterpret_cast<float4*>(&Ks[ss][sc + 8]) =
          *reinterpret_cast<const float4*>(kp + 8);
      const _Float16* vp = &qkvT[base + 128 + (size_t)(sb + ss) * 1536 + sc];
      const float4 v0 = *reinterpret_cast<const float4*>(vp);
      const float4 v1 = *reinterpret_cast<const float4*>(vp + 8);
      const _Float16* vh0 = reinterpret_cast<const _Float16*>(&v0);
      const _Float16* vh1 = reinterpret_cast<const _Float16*>(&v1);
#pragma unroll
      for (int ii = 0; ii < 8; ++ii) Vs[sc + ii][ss] = vh0[ii];
#pragma unroll
      for (int ii = 0; ii < 8; ++ii) Vs[sc + 8 + ii][ss] = vh1[ii];
    }
    __syncthreads();

    // S stripe [tw..tw+16) x [0,64) = Q K^T
    const half8 qa0 = *reinterpret_cast<const half8*>(&Qs[tw + lr][lg * 8]);
    const half8 qa1 = *reinterpret_cast<const half8*>(&Qs[tw + lr][32 + lg * 8]);
    f32x4 sacc[4] = {};
#pragma unroll
    for (int j = 0; j < 4; ++j) {
      const half8 kb0 = *reinterpret_cast<const half8*>(&Ks[j * 16 + lr][lg * 8]);
      const half8 kb1 =
          *reinterpret_cast<const half8*>(&Ks[j * 16 + lr][32 + lg * 8]);
      sacc[j] = __builtin_amdgcn_mfma_f32_16x16x32_f16(qa0, kb0, sacc[j], 0, 0, 0);
      sacc[j] = __builtin_amdgcn_mfma_f32_16x16x32_f16(qa1, kb1, sacc[j], 0, 0, 0);
    }

    // online softmax per owned row r (t = tw + lg*4 + r)
#pragma unroll
    for (int r = 0; r < 4; ++r) {
      float mt = -1e30f;
#pragma unroll
      for (int j = 0; j < 4; ++j) {
        sacc[j][r] *= 0.125f;
        mt = fmaxf(mt, sacc[j][r]);
      }
      mt = fmaxf(mt, __shfl_xor(mt, 1));
      mt = fmaxf(mt, __shfl_xor(mt, 2));
      mt = fmaxf(mt, __shfl_xor(mt, 4));
      mt = fmaxf(mt, __shfl_xor(mt, 8));
      const float mn = fmaxf(m_run[r], mt);
      const float alpha = __expf(m_run[r] - mn);
      m_run[r] = mn;
      float ps = 0.f;
#pragma unroll
      for (int j = 0; j < 4; ++j) {
        const float p = __expf(sacc[j][r] - mn);
        sacc[j][r] = p;
        ps += p;
      }
      ps += __shfl_xor(ps, 1);
      ps += __shfl_xor(ps, 2);
      ps += __shfl_xor(ps, 4);
      ps += __shfl_xor(ps, 8);
      l_run[r] = l_run[r] * alpha + ps;
#pragma unroll
      for (int j = 0; j < 4; ++j) {
        oacc[j][r] *= alpha;
        Ps[tw + lg * 4 + r][j * 16 + lr] = (_Float16)sacc[j][r];
      }
    }

    // PV: own-stripe P (no cross-wave hazard), shared Vs
    const half8 pa0 = *reinterpret_cast<const half8*>(&Ps[tw + lr][lg * 8]);
    const half8 pa1 = *reinterpret_cast<const half8*>(&Ps[tw + lr][32 + lg * 8]);
#pragma unroll
    for (int j = 0; j < 4; ++j) {
      const half8 vb0 = *reinterpret_cast<const half8*>(&Vs[j * 16 + lr][lg * 8]);
      const half8 vb1 =
          *reinterpret_cast<const half8*>(&Vs[j * 16 + lr][32 + lg * 8]);
      oacc[j] = __builtin_amdgcn_mfma_f32_16x16x32_f16(pa0, vb0, oacc[j], 0, 0, 0);
      oacc[j] = __builtin_amdgcn_mfma_f32_16x16x32_f16(pa1, vb1, oacc[j], 0, 0, 0);
    }
  }

  const size_t hbase = (size_t)b * N_ * C_ + head * HD_;
#pragma unroll
  for (int r = 0; r < 4; ++r) {
    const float inv = 1.f / l_run[r];
    const int t = tw + lg * 4 + r;
#pragma unroll
    for (int j = 0; j < 4; ++j)
      hT[hbase + (size_t)(qb + t) * C_ + j * 16 + lr] =
          (_Float16)(oacc[j][r] * inv);
  }
}

// ---------------------------------------------------------------------------
extern "C" void kernel_launch(void* const* d_in, const int* in_sizes, int n_in,
                              void* d_out, int out_size, void* d_ws,
                              size_t ws_size, hipStream_t stream) {
  const float* x = (const float*)d_in[0];
  const float* gn_w = (const float*)d_in[1];
  const float* gn_b = (const float*)d_in[2];
  const float* qkv_w = (const float*)d_in[3];
  const float* proj_w = (const float*)d_in[4];
  const float* proj_b = (const float*)d_in[5];
  float* out = (float*)d_out;

  char* ws = (char*)d_ws;
  _Float16* qw_h = (_Float16*)ws;                              // 1.5 MiB
  _Float16* pw_h = (_Float16*)(ws + (size_t)1572864);          // 0.5 MiB
  _Float16* xnT = (_Float16*)(ws + (size_t)2 * 1024 * 1024);   // 8 MiB
  _Float16* qkvT = (_Float16*)(ws + (size_t)10 * 1024 * 1024); // 24 MiB
  _Float16* hT = (_Float16*)(ws + (size_t)34 * 1024 * 1024);   // 8 MiB

  cvt_kernel<<<dim3(768), 256, 0, stream>>>(qkv_w, qw_h, 3 * C_ * C_);
  cvt_kernel<<<dim3(256), 256, 0, stream>>>(proj_w, pw_h, C_ * C_);
  gn_kernel<<<dim3(B_ * GROUPS_), 256, 0, stream>>>(x, gn_w, gn_b, xnT);
  // qkvT[b][n][m] = sum_k xnT[b][n][k] * qw_h[m][k]
  gemm_tn<true, false><<<dim3(12, 8, B_), 256, 0, stream>>>(
      xnT, (long)N_ * C_, qw_h, 0L, qkvT, (long)N_ * 3 * C_, 3 * C_, C_,
      nullptr, nullptr, 0L);
  attn_mfma<<<dim3(N_ / 64, B_ * NH_), 256, 0, stream>>>(qkvT, hT);
  // out[b][c][n] = sum_k pw_h[c][k] * hT[b][n][k] + proj_b[c] + x[b][c][n]
  gemm_tn<false, true><<<dim3(8, 4, B_), 256, 0, stream>>>(
      pw_h, 0L, hT, (long)N_ * C_, out, (long)C_ * N_, N_, C_,
      proj_b, x, (long)C_ * N_);
}

// Round 3
// 193.338 us; speedup vs baseline: 3.1352x; 1.0818x over previous
//
#include <hip/hip_runtime.h>

#define B_ 8
#define C_ 512
#define N_ 1024
#define GROUPS_ 32
#define CPG_ 16
#define NH_ 8
#define HD_ 64

typedef _Float16 half8 __attribute__((ext_vector_type(8)));
typedef _Float16 half2v __attribute__((ext_vector_type(2)));
typedef float f32x4 __attribute__((ext_vector_type(4)));
typedef float f32x16 __attribute__((ext_vector_type(16)));

// 0.125 (qk softmax scale) * log2(e): folded into Q weights -> softmax in exp2 domain
#define QSCALE 0.18033688011112042f
#define THR_LOG2 11.0f  // defer-max threshold (~e^7.6)

// ---------------------------------------------------------------------------
// Pack weights fp32->fp16, reordering:
//  qkw[1024][512]: row head*128 + r  <- qkv_w row head*192 + r   (r<64: *QSCALE)
//  vw [512][512]:  row head*64  + c  <- qkv_w row head*192+128+c
//  pw [512][512]:  proj_w straight
// ---------------------------------------------------------------------------
__global__ __launch_bounds__(256) void pack_weights(
    const float* __restrict__ qkv_w, const float* __restrict__ proj_w,
    _Float16* __restrict__ qkw, _Float16* __restrict__ vw,
    _Float16* __restrict__ pw) {
  const int R = blockIdx.x * 4 + (threadIdx.x >> 6);  // wave-uniform
  const int k = (threadIdx.x & 63) * 8;
  const float* src;
  _Float16* dst;
  float sc = 1.f;
  if (R < 1024) {
    const int head = R >> 7, r = R & 127;
    src = qkv_w + (size_t)(head * 192 + r) * 512;
    if (r < 64) sc = QSCALE;
    dst = qkw + (size_t)R * 512;
  } else if (R < 1536) {
    const int vr = R - 1024;
    const int head = vr >> 6, c = vr & 63;
    src = qkv_w + (size_t)(head * 192 + 128 + c) * 512;
    dst = vw + (size_t)vr * 512;
  } else {
    src = proj_w + (size_t)(R - 1536) * 512;
    dst = pw + (size_t)(R - 1536) * 512;
  }
  const float4 v0 = *reinterpret_cast<const float4*>(src + k);
  const float4 v1 = *reinterpret_cast<const float4*>(src + k + 4);
  _Float16 h[8] = {(_Float16)(v0.x * sc), (_Float16)(v0.y * sc),
                   (_Float16)(v0.z * sc), (_Float16)(v0.w * sc),
                   (_Float16)(v1.x * sc), (_Float16)(v1.y * sc),
                   (_Float16)(v1.z * sc), (_Float16)(v1.w * sc)};
  *reinterpret_cast<float4*>(dst + k) = *reinterpret_cast<float4*>(h);
}

// ---------------------------------------------------------------------------
// GroupNorm phase 1: per (b,g) mean/rstd -> stats[bg]
// ---------------------------------------------------------------------------
__global__ __launch_bounds__(256) void gn_stats(const float* __restrict__ x,
                                                float2* __restrict__ stats) {
  const int bg = blockIdx.x;
  const int b = bg / GROUPS_, g = bg % GROUPS_;
  const float* xp = x + ((size_t)b * C_ + (size_t)g * CPG_) * N_;
  const int tid = threadIdx.x;
  const int total = CPG_ * N_;  // 16384

  float s = 0.f, ss = 0.f;
  for (int i = tid * 4; i < total; i += 1024) {
    const float4 v = *reinterpret_cast<const float4*>(xp + i);
    s += v.x + v.y + v.z + v.w;
    ss += v.x * v.x + v.y * v.y + v.z * v.z + v.w * v.w;
  }
#pragma unroll
  for (int off = 32; off > 0; off >>= 1) {
    s += __shfl_down(s, off);
    ss += __shfl_down(ss, off);
  }
  __shared__ float red[8];
  if ((tid & 63) == 0) { red[tid >> 6] = s; red[4 + (tid >> 6)] = ss; }
  __syncthreads();
  if (tid == 0) {
    s = red[0] + red[1] + red[2] + red[3];
    ss = red[4] + red[5] + red[6] + red[7];
    const float inv = 1.0f / (float)total;
    const float mu = s * inv;
    const float var = ss * inv - mu * mu;
    stats[bg] = make_float2(mu, rsqrtf(var + 1e-5f));
  }
}

// ---------------------------------------------------------------------------
// GroupNorm phase 2: normalize + transpose to xnT[b][n][c] fp16.
// Block = (16 n) x (512 c); writes full 1KB rows (coalesced).
// ---------------------------------------------------------------------------
__global__ __launch_bounds__(256) void gn_norm(const float* __restrict__ x,
                                               const float* __restrict__ gw,
                                               const float* __restrict__ gb,
                                               const float2* __restrict__ stats,
                                               _Float16* __restrict__ xnT) {
  const int n0 = blockIdx.x * 16;
  const int b = blockIdx.y;
  __shared__ _Float16 T[16][520];
  __shared__ float wsh[512], bsh[512];
  const int tid = threadIdx.x;
  for (int c = tid; c < 512; c += 256) {
    const float2 st = stats[b * 32 + (c >> 4)];
    const float wv = gw[c] * st.y;
    wsh[c] = wv;
    bsh[c] = gb[c] - st.x * wv;
  }
  __syncthreads();
  {
    const int n = tid & 15;
    const int cb = tid >> 4;
    const float* xb = x + (size_t)b * C_ * N_ + n0 + n;
#pragma unroll
    for (int i = 0; i < 32; ++i) {
      const int c = i * 16 + cb;
      T[n][c] = (_Float16)(xb[(size_t)c * N_] * wsh[c] + bsh[c]);
    }
  }
  __syncthreads();
  const int row = tid >> 4;
  const int seg = tid & 15;
  _Float16* dst = &xnT[((size_t)b * N_ + n0 + row) * C_ + seg * 32];
  const _Float16* srcp = &T[row][seg * 32];
  *reinterpret_cast<float4*>(dst) = *reinterpret_cast<const float4*>(srcp);
  *reinterpret_cast<float4*>(dst + 8) = *reinterpret_cast<const float4*>(srcp + 8);
  *reinterpret_cast<float4*>(dst + 16) = *reinterpret_cast<const float4*>(srcp + 16);
  *reinterpret_cast<float4*>(dst + 24) = *reinterpret_cast<const float4*>(srcp + 24);
}

// ---------------------------------------------------------------------------
// NT-GEMM via MFMA fp16 (unchanged from round 2; verified).
// D[ar][bc] = sum_k A[ar][k]*B[bc][k]; 128x128 tile, BK=32, 4 waves.
// ---------------------------------------------------------------------------
template <bool OUT_HALF, bool EPI>
__global__ __launch_bounds__(256) void gemm_tn(
    const _Float16* __restrict__ A, long strideAb,
    const _Float16* __restrict__ Bm, long strideBb,
    void* __restrict__ D, long strideDb, int ldd, int K,
    const float* __restrict__ bias, const float* __restrict__ resid,
    long strideRb) {
  const int bc0 = blockIdx.x * 128;
  const int ar0 = blockIdx.y * 128;
  const int b = blockIdx.z;
  const _Float16* Ab = A + (size_t)b * strideAb;
  const _Float16* Bb = Bm + (size_t)b * strideBb;

  __shared__ _Float16 As[128][40];
  __shared__ _Float16 Bs[128][40];

  const int tid = threadIdx.x;
  const int lane = tid & 63;
  const int wid = tid >> 6;
  const int war = (wid >> 1) * 64;
  const int wbc = (wid & 1) * 64;
  const int lg = lane >> 4;
  const int lr = lane & 15;

  const int srow = tid >> 1;
  const int skoff = (tid & 1) * 16;

  f32x4 acc[4][4] = {};

  for (int k0 = 0; k0 < K; k0 += 32) {
    __syncthreads();
    const float4 av0 = *reinterpret_cast<const float4*>(
        &Ab[(size_t)(ar0 + srow) * K + k0 + skoff]);
    const float4 av1 = *reinterpret_cast<const float4*>(
        &Ab[(size_t)(ar0 + srow) * K + k0 + skoff + 8]);
    const float4 bv0 = *reinterpret_cast<const float4*>(
        &Bb[(size_t)(bc0 + srow) * K + k0 + skoff]);
    const float4 bv1 = *reinterpret_cast<const float4*>(
        &Bb[(size_t)(bc0 + srow) * K + k0 + skoff + 8]);
    *reinterpret_cast<float4*>(&As[srow][skoff]) = av0;
    *reinterpret_cast<float4*>(&As[srow][skoff + 8]) = av1;
    *reinterpret_cast<float4*>(&Bs[srow][skoff]) = bv0;
    *reinterpret_cast<float4*>(&Bs[srow][skoff + 8]) = bv1;
    __syncthreads();

    half8 af[4], bf[4];
#pragma unroll
    for (int i = 0; i < 4; ++i)
      af[i] = *reinterpret_cast<const half8*>(&As[war + i * 16 + lr][lg * 8]);
#pragma unroll
    for (int j = 0; j < 4; ++j)
      bf[j] = *reinterpret_cast<const half8*>(&Bs[wbc + j * 16 + lr][lg * 8]);
#pragma unroll
    for (int i = 0; i < 4; ++i)
#pragma unroll
      for (int j = 0; j < 4; ++j)
        acc[i][j] = __builtin_amdgcn_mfma_f32_16x16x32_f16(af[i], bf[j],
                                                           acc[i][j], 0, 0, 0);
  }

  if (OUT_HALF) {
    _Float16* Dp = (_Float16*)D + (size_t)b * strideDb;
#pragma unroll
    for (int i = 0; i < 4; ++i)
#pragma unroll
      for (int r = 0; r < 4; ++r) {
        const int row = ar0 + war + i * 16 + lg * 4 + r;
#pragma unroll
        for (int j = 0; j < 4; ++j) {
          const int col = bc0 + wbc + j * 16 + lr;
          Dp[(size_t)row * ldd + col] = (_Float16)acc[i][j][r];
        }
      }
  }
  if (EPI) {
    float* Dp = (float*)D + (size_t)b * strideDb;
    const float* Rp = resid + (size_t)b * strideRb;
#pragma unroll
    for (int i = 0; i < 4; ++i)
#pragma unroll
      for (int r = 0; r < 4; ++r) {
        const int row = ar0 + war + i * 16 + lg * 4 + r;
        const float bv = bias[row];
#pragma unroll
        for (int j = 0; j < 4; ++j) {
          const int col = bc0 + wbc + j * 16 + lr;
          const size_t off = (size_t)row * ldd + col;
          Dp[off] = acc[i][j][r] + bv + Rp[off];
        }
      }
  }
}

// ---------------------------------------------------------------------------
// Flash attention, 32x32x16 MFMA, swapped QK^T (S^T = K·Q), in-register P.
// Block: 256 queries x one (b,head); 4 waves x 64 queries (2 t-tiles of 32).
// qkT[b][n][head*128 + {0..63 Q(pre-scaled), 64..127 K}], vT[bh*64+c][n].
// Softmax in exp2 domain. Output hT[b][n][head*64+c] fp16.
//
// 32x32x16 layouts (m74/m101): A/B-frag: lane row = l&31, k = (l>>5)*8+e.
// C/D: col = lane&31, row = (reg&3) + 8*(reg>>2) + 4*(lane>>5).
// ---------------------------------------------------------------------------
__global__ __launch_bounds__(256, 1) void attn_mfma(
    const _Float16* __restrict__ qkT, const _Float16* __restrict__ vT,
    _Float16* __restrict__ hT) {
  const int qb = blockIdx.x * 256;
  const int bh = blockIdx.y;
  const int b = bh >> 3, head = bh & 7;
  const int tid = threadIdx.x;
  const int lane = tid & 63;
  const int w = tid >> 6;
  const int l31 = lane & 31;
  const int lg2 = lane >> 5;

  __shared__ _Float16 Ks[64][72];  // [s][c]
  __shared__ _Float16 Vs[64][72];  // [c][s]  (vT is already transposed)

  const size_t qkbase = (size_t)b * N_ * 1024;

  // Q fragments held in registers for the whole kernel (pre-scaled by QSCALE)
  half8 bfq[2][4];
#pragma unroll
  for (int jt = 0; jt < 2; ++jt)
#pragma unroll
    for (int kc = 0; kc < 4; ++kc)
      bfq[jt][kc] = *reinterpret_cast<const half8*>(
          &qkT[qkbase + (size_t)(qb + w * 64 + jt * 32 + l31) * 1024 +
               head * 128 + kc * 16 + lg2 * 8]);

  // staging: thread -> (row sr, col-seg sc); K row = s, V row = c
  const int sr = tid >> 2;
  const int sc = (tid & 3) * 16;
  const _Float16* kp0 = qkT + qkbase + (size_t)sr * 1024 + head * 128 + 64 + sc;
  const _Float16* vp0 = vT + ((size_t)bh * 64 + sr) * 1024 + sc;

  float4 kreg0 = *reinterpret_cast<const float4*>(kp0);
  float4 kreg1 = *reinterpret_cast<const float4*>(kp0 + 8);
  float4 vreg0 = *reinterpret_cast<const float4*>(vp0);
  float4 vreg1 = *reinterpret_cast<const float4*>(vp0 + 8);

  f32x16 oacc[2][2];  // [jt][ct]
#pragma unroll
  for (int jt = 0; jt < 2; ++jt)
#pragma unroll
    for (int ct = 0; ct < 2; ++ct)
#pragma unroll
      for (int r = 0; r < 16; ++r) oacc[jt][ct][r] = 0.f;
  float m_run[2] = {-1e30f, -1e30f};
  float l_run[2] = {0.f, 0.f};

  for (int t = 0; t < 16; ++t) {
    __syncthreads();  // everyone done reading Ks/Vs of prev tile
    *reinterpret_cast<float4*>(&Ks[sr][sc]) = kreg0;
    *reinterpret_cast<float4*>(&Ks[sr][sc + 8]) = kreg1;
    *reinterpret_cast<float4*>(&Vs[sr][sc]) = vreg0;
    *reinterpret_cast<float4*>(&Vs[sr][sc + 8]) = vreg1;
    __syncthreads();
    {  // prefetch next tile into registers (latency hidden by compute below)
      const int sbn = (t < 15) ? (t + 1) * 64 : 960;
      kreg0 = *reinterpret_cast<const float4*>(kp0 + (size_t)sbn * 1024);
      kreg1 = *reinterpret_cast<const float4*>(kp0 + (size_t)sbn * 1024 + 8);
      vreg0 = *reinterpret_cast<const float4*>(vp0 + sbn);
      vreg1 = *reinterpret_cast<const float4*>(vp0 + sbn + 8);
    }

    // S^T = K·Q : sacc[jt][st], row = s-local, col = t-local (one query/lane)
    f32x16 sacc[2][2];
#pragma unroll
    for (int jt = 0; jt < 2; ++jt)
#pragma unroll
      for (int st = 0; st < 2; ++st)
#pragma unroll
        for (int r = 0; r < 16; ++r) sacc[jt][st][r] = 0.f;
#pragma unroll
    for (int st = 0; st < 2; ++st)
#pragma unroll
      for (int kc = 0; kc < 4; ++kc) {
        const half8 af = *reinterpret_cast<const half8*>(
            &Ks[st * 32 + l31][kc * 16 + lg2 * 8]);
        sacc[0][st] = __builtin_amdgcn_mfma_f32_32x32x16_f16(
            af, bfq[0][kc], sacc[0][st], 0, 0, 0);
        sacc[1][st] = __builtin_amdgcn_mfma_f32_32x32x16_f16(
            af, bfq[1][kc], sacc[1][st], 0, 0, 0);
      }

    // online softmax (exp2 domain) + pack P to PV A-fragments, per t-tile
    half8 pa[2][4];
#pragma unroll
    for (int jt = 0; jt < 2; ++jt) {
      float mt = -1e30f;
#pragma unroll
      for (int st = 0; st < 2; ++st)
#pragma unroll
        for (int r = 0; r < 16; ++r) mt = fmaxf(mt, sacc[jt][st][r]);
      mt = fmaxf(mt, __shfl_xor(mt, 32));
      if (!__all(mt <= m_run[jt] + THR_LOG2)) {  // defer-max: rescale rarely
        const float mn = fmaxf(m_run[jt], mt);
        const float alpha = exp2f(m_run[jt] - mn);
        m_run[jt] = mn;
        l_run[jt] *= alpha;
#pragma unroll
        for (int r = 0; r < 16; ++r) {
          const int qrow = (r & 3) + 8 * (r >> 2) + 4 * lg2;
          const float ar = __shfl(alpha, qrow);
          oacc[jt][0][r] *= ar;
          oacc[jt][1][r] *= ar;
        }
      }
      const float mr = m_run[jt];
      float ps = 0.f;
#pragma unroll
      for (int st = 0; st < 2; ++st)
#pragma unroll
        for (int r = 0; r < 16; ++r) {
          const float p = exp2f(sacc[jt][st][r] - mr);
          sacc[jt][st][r] = p;
          ps += p;
        }
      ps += __shfl_xor(ps, 32);
      l_run[jt] += ps;

      // pack pairs (s even, s odd) -> u32 words; w[st][m], m = reg/2
      unsigned int wo[2][8];
#pragma unroll
      for (int st = 0; st < 2; ++st)
#pragma unroll
        for (int m = 0; m < 8; ++m) {
          union { half2v h; unsigned int u; } cv;
          cv.h.x = (_Float16)sacc[jt][st][2 * m];
          cv.h.y = (_Float16)sacc[jt][st][2 * m + 1];
          wo[st][m] = cv.u;
        }
      // A-frag(kc): k-elems s = kc*16 + lg2*8 + 0..7.
      // lo half from lane(lg2'=0,q), hi half from lane(lg2'=1,q):
      //   W0,W1 = words[4(kc&1)+2*lg2 + {0,1}] of lane(0,q)
      //   W2,W3 = same words of lane(1,q)      (shfl_xor(·,32) emulation)
#pragma unroll
      for (int kc = 0; kc < 4; ++kc) {
        const int st = kc >> 1;
        const int base = 4 * (kc & 1);
        const unsigned int a0 = wo[st][base], a1 = wo[st][base + 1];
        const unsigned int a2 = wo[st][base + 2], a3 = wo[st][base + 3];
        const unsigned int x0 = __shfl_xor(a0, 32);
        const unsigned int x1 = __shfl_xor(a1, 32);
        const unsigned int x2 = __shfl_xor(a2, 32);
        const unsigned int x3 = __shfl_xor(a3, 32);
        union { unsigned int u[4]; half8 h; } fr;
        fr.u[0] = lg2 ? x2 : a0;
        fr.u[1] = lg2 ? x3 : a1;
        fr.u[2] = lg2 ? a2 : x0;
        fr.u[3] = lg2 ? a3 : x1;
        pa[jt][kc] = fr.h;
      }
    }

    // O += P·V : A = P rows t (in regs), B = V^T rows c (LDS)
#pragma unroll
    for (int ct = 0; ct < 2; ++ct)
#pragma unroll
      for (int ks = 0; ks < 4; ++ks) {
        const half8 vf = *reinterpret_cast<const half8*>(
            &Vs[ct * 32 + l31][ks * 16 + lg2 * 8]);
        oacc[0][ct] = __builtin_amdgcn_mfma_f32_32x32x16_f16(
            pa[0][ks], vf, oacc[0][ct], 0, 0, 0);
        oacc[1][ct] = __builtin_amdgcn_mfma_f32_32x32x16_f16(
            pa[1][ks], vf, oacc[1][ct], 0, 0, 0);
      }
  }

  // normalize + store: hT[b][qb + w*64 + jt*32 + trow][head*64 + ct*32 + l31]
  const size_t hbase = ((size_t)b * N_ + qb) * C_ + head * 64;
#pragma unroll
  for (int jt = 0; jt < 2; ++jt) {
    const float linv = 1.f / l_run[jt];
#pragma unroll
    for (int r = 0; r < 16; ++r) {
      const int qrow = (r & 3) + 8 * (r >> 2) + 4 * lg2;
      const float li = __shfl(linv, qrow);
      const size_t rowoff = hbase + (size_t)(w * 64 + jt * 32 + qrow) * C_;
#pragma unroll
      for (int ct = 0; ct < 2; ++ct)
        hT[rowoff + ct * 32 + l31] = (_Float16)(oacc[jt][ct][r] * li);
    }
  }
}

// ---------------------------------------------------------------------------
extern "C" void kernel_launch(void* const* d_in, const int* in_sizes, int n_in,
                              void* d_out, int out_size, void* d_ws,
                              size_t ws_size, hipStream_t stream) {
  const float* x = (const float*)d_in[0];
  const float* gn_w = (const float*)d_in[1];
  const float* gn_b = (const float*)d_in[2];
  const float* qkv_w = (const float*)d_in[3];
  const float* proj_w = (const float*)d_in[4];
  const float* proj_b = (const float*)d_in[5];
  float* out = (float*)d_out;

  char* ws = (char*)d_ws;
  const size_t MB = 1024 * 1024;
  _Float16* qkw = (_Float16*)(ws);                 // 1 MiB
  _Float16* vw = (_Float16*)(ws + 1 * MB);         // 0.5 MiB
  _Float16* pw = (_Float16*)(ws + 3 * MB / 2);     // 0.5 MiB
  float2* stats = (float2*)(ws + 2 * MB);          // 2 KiB
  _Float16* xnT = (_Float16*)(ws + 3 * MB);        // 8 MiB  [b][n][512]
  _Float16* qkT = (_Float16*)(ws + 11 * MB);       // 16 MiB [b][n][1024]
  _Float16* vT = (_Float16*)(ws + 27 * MB);        // 8 MiB  [bh*64+c][n]
  _Float16* hT = (_Float16*)(ws + 35 * MB);        // 8 MiB  [b][n][512]

  pack_weights<<<dim3(512), 256, 0, stream>>>(qkv_w, proj_w, qkw, vw, pw);
  gn_stats<<<dim3(B_ * GROUPS_), 256, 0, stream>>>(x, stats);
  gn_norm<<<dim3(64, B_), 256, 0, stream>>>(x, gn_w, gn_b, stats, xnT);
  // qkT[b][n][ch] = sum_k xnT[b][n][k] * qkw[ch][k]
  gemm_tn<true, false><<<dim3(8, 8, B_), 256, 0, stream>>>(
      xnT, (long)N_ * C_, qkw, 0L, qkT, (long)N_ * 1024, 1024, C_,
      nullptr, nullptr, 0L);
  // vT[b][vr][n] = sum_k vw[vr][k] * xnT[b][n][k]   (free V transpose)
  gemm_tn<true, false><<<dim3(8, 4, B_), 256, 0, stream>>>(
      vw, 0L, xnT, (long)N_ * C_, vT, (long)512 * 1024, 1024, C_,
      nullptr, nullptr, 0L);
  attn_mfma<<<dim3(N_ / 256, B_ * NH_), 256, 0, stream>>>(qkT, vT, hT);
  // out[b][c][n] = sum_k pw[c][k] * hT[b][n][k] + proj_b[c] + x[b][c][n]
  gemm_tn<false, true><<<dim3(8, 4, B_), 256, 0, stream>>>(
      pw, 0L, hT, (long)N_ * C_, out, (long)C_ * N_, N_, C_,
      proj_b, x, (long)C_ * N_);
}

// Round 4
// 171.084 us; speedup vs baseline: 3.5430x; 1.1301x over previous
//
#include <hip/hip_runtime.h>

#define B_ 8
#define C_ 512
#define N_ 1024
#define GROUPS_ 32
#define CPG_ 16
#define NH_ 8
#define HD_ 64

typedef _Float16 half8 __attribute__((ext_vector_type(8)));
typedef _Float16 half2v __attribute__((ext_vector_type(2)));
typedef float f32x4 __attribute__((ext_vector_type(4)));
typedef float f32x16 __attribute__((ext_vector_type(16)));

// 0.125 (qk softmax scale) * log2(e): folded into Q weights -> exp2-domain softmax
#define QSCALE 0.18033688011112042f
#define THR_LOG2 11.0f

// async global->LDS, 16B per lane; LDS dest is wave-uniform base + lane*16
__device__ __forceinline__ void gload_lds16(const void* g, void* l) {
  __builtin_amdgcn_global_load_lds(
      (const __attribute__((address_space(1))) unsigned int*)g,
      (__attribute__((address_space(3))) unsigned int*)l, 16, 0, 0);
}

// ---------------------------------------------------------------------------
// prep: blocks 0..511 pack weights fp32->fp16 (reordered);
//       blocks 512..767 compute GroupNorm stats.
// ---------------------------------------------------------------------------
__global__ __launch_bounds__(256) void prep(
    const float* __restrict__ qkv_w, const float* __restrict__ proj_w,
    const float* __restrict__ x, _Float16* __restrict__ qkw,
    _Float16* __restrict__ vw, _Float16* __restrict__ pw,
    float2* __restrict__ stats) {
  const int tid = threadIdx.x;
  if (blockIdx.x < 512) {
    const int R = blockIdx.x * 4 + (tid >> 6);
    const int k = (tid & 63) * 8;
    const float* src;
    _Float16* dst;
    float sc = 1.f;
    if (R < 1024) {
      const int head = R >> 7, r = R & 127;
      src = qkv_w + (size_t)(head * 192 + r) * 512;
      if (r < 64) sc = QSCALE;
      dst = qkw + (size_t)R * 512;
    } else if (R < 1536) {
      const int vr = R - 1024;
      const int head = vr >> 6, c = vr & 63;
      src = qkv_w + (size_t)(head * 192 + 128 + c) * 512;
      dst = vw + (size_t)vr * 512;
    } else {
      src = proj_w + (size_t)(R - 1536) * 512;
      dst = pw + (size_t)(R - 1536) * 512;
    }
    const float4 v0 = *reinterpret_cast<const float4*>(src + k);
    const float4 v1 = *reinterpret_cast<const float4*>(src + k + 4);
    _Float16 h[8] = {(_Float16)(v0.x * sc), (_Float16)(v0.y * sc),
                     (_Float16)(v0.z * sc), (_Float16)(v0.w * sc),
                     (_Float16)(v1.x * sc), (_Float16)(v1.y * sc),
                     (_Float16)(v1.z * sc), (_Float16)(v1.w * sc)};
    *reinterpret_cast<float4*>(dst + k) = *reinterpret_cast<float4*>(h);
  } else {
    const int bg = blockIdx.x - 512;
    const int b = bg / GROUPS_, g = bg % GROUPS_;
    const float* xp = x + ((size_t)b * C_ + (size_t)g * CPG_) * N_;
    const int total = CPG_ * N_;
    float s = 0.f, ss = 0.f;
    for (int i = tid * 4; i < total; i += 1024) {
      const float4 v = *reinterpret_cast<const float4*>(xp + i);
      s += v.x + v.y + v.z + v.w;
      ss += v.x * v.x + v.y * v.y + v.z * v.z + v.w * v.w;
    }
#pragma unroll
    for (int off = 32; off > 0; off >>= 1) {
      s += __shfl_down(s, off);
      ss += __shfl_down(ss, off);
    }
    __shared__ float red[8];
    if ((tid & 63) == 0) { red[tid >> 6] = s; red[4 + (tid >> 6)] = ss; }
    __syncthreads();
    if (tid == 0) {
      s = red[0] + red[1] + red[2] + red[3];
      ss = red[4] + red[5] + red[6] + red[7];
      const float inv = 1.0f / (float)total;
      const float mu = s * inv;
      const float var = ss * inv - mu * mu;
      stats[bg] = make_float2(mu, rsqrtf(var + 1e-5f));
    }
  }
}

// ---------------------------------------------------------------------------
// GroupNorm normalize + transpose to xnT[b][n][c] fp16 (1KB coalesced rows).
// ---------------------------------------------------------------------------
__global__ __launch_bounds__(256) void gn_norm(const float* __restrict__ x,
                                               const float* __restrict__ gw,
                                               const float* __restrict__ gb,
                                               const float2* __restrict__ stats,
                                               _Float16* __restrict__ xnT) {
  const int n0 = blockIdx.x * 16;
  const int b = blockIdx.y;
  __shared__ _Float16 T[16][520];
  __shared__ float wsh[512], bsh[512];
  const int tid = threadIdx.x;
  for (int c = tid; c < 512; c += 256) {
    const float2 st = stats[b * 32 + (c >> 4)];
    const float wv = gw[c] * st.y;
    wsh[c] = wv;
    bsh[c] = gb[c] - st.x * wv;
  }
  __syncthreads();
  {
    const int n = tid & 15;
    const int cb = tid >> 4;
    const float* xb = x + (size_t)b * C_ * N_ + n0 + n;
#pragma unroll
    for (int i = 0; i < 32; ++i) {
      const int c = i * 16 + cb;
      T[n][c] = (_Float16)(xb[(size_t)c * N_] * wsh[c] + bsh[c]);
    }
  }
  __syncthreads();
  const int row = tid >> 4;
  const int seg = tid & 15;
  _Float16* dst = &xnT[((size_t)b * N_ + n0 + row) * C_ + seg * 32];
  const _Float16* srcp = &T[row][seg * 32];
  *reinterpret_cast<float4*>(dst) = *reinterpret_cast<const float4*>(srcp);
  *reinterpret_cast<float4*>(dst + 8) = *reinterpret_cast<const float4*>(srcp + 8);
  *reinterpret_cast<float4*>(dst + 16) = *reinterpret_cast<const float4*>(srcp + 16);
  *reinterpret_cast<float4*>(dst + 24) = *reinterpret_cast<const float4*>(srcp + 24);
}

// ---------------------------------------------------------------------------
// NT-GEMM v2: D[ar][bc] = sum_k A[ar][k]*B[bc][k].  128x128 tile, BK=64,
// double-buffered LDS staged via global_load_lds (16B), XOR-swizzled granules:
//   LDS[row][gslot] = A[row][gslot ^ (row&7)]  (source pre-swizzle),
//   read granule (4*kc+lg) ^ (row&7)  -> conflict-free ds_read_b128.
// 2-phase: issue next-tile loads BEFORE compute; barrier drains vmcnt.
// ---------------------------------------------------------------------------
template <bool OUT_HALF, bool EPI>
__global__ __launch_bounds__(256, 2) void gemm_tn(
    const _Float16* __restrict__ A, long strideAb,
    const _Float16* __restrict__ Bm, long strideBb,
    void* __restrict__ D, long strideDb, int ldd, int K,
    const float* __restrict__ bias, const float* __restrict__ resid,
    long strideRb) {
  const int bc0 = blockIdx.x * 128;
  const int ar0 = blockIdx.y * 128;
  const int b = blockIdx.z;
  const _Float16* Ab = A + (size_t)b * strideAb;
  const _Float16* Bb = Bm + (size_t)b * strideBb;

  __shared__ _Float16 As[2][128][64];
  __shared__ _Float16 Bs[2][128][64];

  const int tid = threadIdx.x;
  const int lane = tid & 63;
  const int wid = tid >> 6;
  const int war = (wid >> 1) * 64;
  const int wbc = (wid & 1) * 64;
  const int lg = lane >> 4;
  const int lr = lane & 15;

  // staging: wave wid, iter i covers rows rb..rb+7 (8 rows x 8 granules)
  const int srow = lane >> 3;                 // 0..7 within the 8-row band
  const int sgr = (lane & 7) ^ srow;          // pre-swizzled source granule

#define STAGE(buf, koff)                                                     \
  _Pragma("unroll") for (int i = 0; i < 4; ++i) {                            \
    const int rb = (i * 4 + wid) * 8;                                        \
    gload_lds16(&Ab[(size_t)(ar0 + rb + srow) * K + (koff) + sgr * 8],       \
                &As[buf][rb][0]);                                            \
    gload_lds16(&Bb[(size_t)(bc0 + rb + srow) * K + (koff) + sgr * 8],       \
                &Bs[buf][rb][0]);                                            \
  }

  f32x4 acc[4][4] = {};

  STAGE(0, 0)
  __syncthreads();

  const int nsteps = K >> 6;
  int cur = 0;
  for (int step = 0; step < nsteps; ++step) {
    if (step + 1 < nsteps) { STAGE(cur ^ 1, (step + 1) << 6) }
    const half8* Ah = reinterpret_cast<const half8*>(&As[cur][0][0]);
    const half8* Bh = reinterpret_cast<const half8*>(&Bs[cur][0][0]);
#pragma unroll
    for (int kc = 0; kc < 2; ++kc) {
      half8 af[4], bf[4];
#pragma unroll
      for (int i = 0; i < 4; ++i)
        af[i] = Ah[(war + i * 16 + lr) * 8 + ((4 * kc + lg) ^ (lr & 7))];
#pragma unroll
      for (int j = 0; j < 4; ++j)
        bf[j] = Bh[(wbc + j * 16 + lr) * 8 + ((4 * kc + lg) ^ (lr & 7))];
#pragma unroll
      for (int i = 0; i < 4; ++i)
#pragma unroll
        for (int j = 0; j < 4; ++j)
          acc[i][j] = __builtin_amdgcn_mfma_f32_16x16x32_f16(af[i], bf[j],
                                                             acc[i][j], 0, 0, 0);
    }
    __syncthreads();  // drains vmcnt (next buf staged) + lgkmcnt
    cur ^= 1;
  }
#undef STAGE

  if (OUT_HALF) {
    _Float16* Dp = (_Float16*)D + (size_t)b * strideDb;
#pragma unroll
    for (int i = 0; i < 4; ++i)
#pragma unroll
      for (int r = 0; r < 4; ++r) {
        const int row = ar0 + war + i * 16 + lg * 4 + r;
#pragma unroll
        for (int j = 0; j < 4; ++j) {
          const int col = bc0 + wbc + j * 16 + lr;
          Dp[(size_t)row * ldd + col] = (_Float16)acc[i][j][r];
        }
      }
  }
  if (EPI) {
    float* Dp = (float*)D + (size_t)b * strideDb;
    const float* Rp = resid + (size_t)b * strideRb;
#pragma unroll
    for (int i = 0; i < 4; ++i)
#pragma unroll
      for (int r = 0; r < 4; ++r) {
        const int row = ar0 + war + i * 16 + lg * 4 + r;
        const float bv = bias[row];
#pragma unroll
        for (int j = 0; j < 4; ++j) {
          const int col = bc0 + wbc + j * 16 + lr;
          const size_t off = (size_t)row * ldd + col;
          Dp[off] = acc[i][j][r] + bv + Rp[off];
        }
      }
  }
}

// ---------------------------------------------------------------------------
// Flash attention, 32x32x16 MFMA, swapped QK^T, in-register P.
// QBLK=128: 4 waves x 32 queries; grid (8, B*NH) = 512 blocks -> 8 waves/CU.
// ---------------------------------------------------------------------------
__global__ __launch_bounds__(256, 2) void attn_mfma(
    const _Float16* __restrict__ qkT, const _Float16* __restrict__ vT,
    _Float16* __restrict__ hT) {
  const int qb = blockIdx.x * 128;
  const int bh = blockIdx.y;
  const int b = bh >> 3, head = bh & 7;
  const int tid = threadIdx.x;
  const int lane = tid & 63;
  const int w = tid >> 6;
  const int l31 = lane & 31;
  const int lg2 = lane >> 5;

  __shared__ _Float16 Ks[64][72];
  __shared__ _Float16 Vs[64][72];

  const size_t qkbase = (size_t)b * N_ * 1024;

  // Q fragments in registers (pre-scaled by QSCALE at weight pack)
  half8 bfq[4];
#pragma unroll
  for (int kc = 0; kc < 4; ++kc)
    bfq[kc] = *reinterpret_cast<const half8*>(
        &qkT[qkbase + (size_t)(qb + w * 32 + l31) * 1024 + head * 128 +
             kc * 16 + lg2 * 8]);

  const int sr = tid >> 2;
  const int sc = (tid & 3) * 16;
  const _Float16* kp0 = qkT + qkbase + (size_t)sr * 1024 + head * 128 + 64 + sc;
  const _Float16* vp0 = vT + ((size_t)bh * 64 + sr) * 1024 + sc;

  float4 kreg0 = *reinterpret_cast<const float4*>(kp0);
  float4 kreg1 = *reinterpret_cast<const float4*>(kp0 + 8);
  float4 vreg0 = *reinterpret_cast<const float4*>(vp0);
  float4 vreg1 = *reinterpret_cast<const float4*>(vp0 + 8);

  f32x16 oacc[2];
#pragma unroll
  for (int ct = 0; ct < 2; ++ct)
#pragma unroll
    for (int r = 0; r < 16; ++r) oacc[ct][r] = 0.f;
  float m_run = -1e30f, l_run = 0.f;

  for (int t = 0; t < 16; ++t) {
    __syncthreads();
    *reinterpret_cast<float4*>(&Ks[sr][sc]) = kreg0;
    *reinterpret_cast<float4*>(&Ks[sr][sc + 8]) = kreg1;
    *reinterpret_cast<float4*>(&Vs[sr][sc]) = vreg0;
    *reinterpret_cast<float4*>(&Vs[sr][sc + 8]) = vreg1;
    __syncthreads();
    {
      const int sbn = (t < 15) ? (t + 1) * 64 : 960;
      kreg0 = *reinterpret_cast<const float4*>(kp0 + (size_t)sbn * 1024);
      kreg1 = *reinterpret_cast<const float4*>(kp0 + (size_t)sbn * 1024 + 8);
      vreg0 = *reinterpret_cast<const float4*>(vp0 + sbn);
      vreg1 = *reinterpret_cast<const float4*>(vp0 + sbn + 8);
    }

    // S^T = K·Q (one query column per lane)
    f32x16 sacc[2];
#pragma unroll
    for (int st = 0; st < 2; ++st)
#pragma unroll
      for (int r = 0; r < 16; ++r) sacc[st][r] = 0.f;
    __builtin_amdgcn_s_setprio(1);
#pragma unroll
    for (int st = 0; st < 2; ++st)
#pragma unroll
      for (int kc = 0; kc < 4; ++kc) {
        const half8 af = *reinterpret_cast<const half8*>(
            &Ks[st * 32 + l31][kc * 16 + lg2 * 8]);
        sacc[st] = __builtin_amdgcn_mfma_f32_32x32x16_f16(af, bfq[kc],
                                                          sacc[st], 0, 0, 0);
      }
    __builtin_amdgcn_s_setprio(0);

    // online softmax (exp2 domain), defer-max
    float mt = -1e30f;
#pragma unroll
    for (int st = 0; st < 2; ++st)
#pragma unroll
      for (int r = 0; r < 16; ++r) mt = fmaxf(mt, sacc[st][r]);
    mt = fmaxf(mt, __shfl_xor(mt, 32));
    if (!__all(mt <= m_run + THR_LOG2)) {
      const float mn = fmaxf(m_run, mt);
      const float alpha = exp2f(m_run - mn);
      m_run = mn;
      l_run *= alpha;
#pragma unroll
      for (int r = 0; r < 16; ++r) {
        const int qrow = (r & 3) + 8 * (r >> 2) + 4 * lg2;
        const float ar = __shfl(alpha, qrow);
        oacc[0][r] *= ar;
        oacc[1][r] *= ar;
      }
    }
    const float mr = m_run;
    float ps = 0.f;
#pragma unroll
    for (int st = 0; st < 2; ++st)
#pragma unroll
      for (int r = 0; r < 16; ++r) {
        const float p = exp2f(sacc[st][r] - mr);
        sacc[st][r] = p;
        ps += p;
      }
    ps += __shfl_xor(ps, 32);
    l_run += ps;

    // pack P -> PV A-fragments (cross-half exchange via shfl_xor 32)
    half8 pa[4];
    {
      unsigned int wo[2][8];
#pragma unroll
      for (int st = 0; st < 2; ++st)
#pragma unroll
        for (int m = 0; m < 8; ++m) {
          union { half2v h; unsigned int u; } cv;
          cv.h.x = (_Float16)sacc[st][2 * m];
          cv.h.y = (_Float16)sacc[st][2 * m + 1];
          wo[st][m] = cv.u;
        }
#pragma unroll
      for (int kc = 0; kc < 4; ++kc) {
        const int st = kc >> 1;
        const int base = 4 * (kc & 1);
        const unsigned int a0 = wo[st][base], a1 = wo[st][base + 1];
        const unsigned int a2 = wo[st][base + 2], a3 = wo[st][base + 3];
        const unsigned int x0 = __shfl_xor(a0, 32);
        const unsigned int x1 = __shfl_xor(a1, 32);
        const unsigned int x2 = __shfl_xor(a2, 32);
        const unsigned int x3 = __shfl_xor(a3, 32);
        union { unsigned int u[4]; half8 h; } fr;
        fr.u[0] = lg2 ? x2 : a0;
        fr.u[1] = lg2 ? x3 : a1;
        fr.u[2] = lg2 ? a2 : x0;
        fr.u[3] = lg2 ? a3 : x1;
        pa[kc] = fr.h;
      }
    }

    // O += P·V
    __builtin_amdgcn_s_setprio(1);
#pragma unroll
    for (int ct = 0; ct < 2; ++ct)
#pragma unroll
      for (int ks = 0; ks < 4; ++ks) {
        const half8 vf = *reinterpret_cast<const half8*>(
            &Vs[ct * 32 + l31][ks * 16 + lg2 * 8]);
        oacc[ct] = __builtin_amdgcn_mfma_f32_32x32x16_f16(pa[ks], vf,
                                                          oacc[ct], 0, 0, 0);
      }
    __builtin_amdgcn_s_setprio(0);
  }

  const size_t hbase = ((size_t)b * N_ + qb) * C_ + head * 64;
  const float linv = 1.f / l_run;
#pragma unroll
  for (int r = 0; r < 16; ++r) {
    const int qrow = (r & 3) + 8 * (r >> 2) + 4 * lg2;
    const float li = __shfl(linv, qrow);
    const size_t rowoff = hbase + (size_t)(w * 32 + qrow) * C_;
#pragma unroll
    for (int ct = 0; ct < 2; ++ct)
      hT[rowoff + ct * 32 + l31] = (_Float16)(oacc[ct][r] * li);
  }
}

// ---------------------------------------------------------------------------
extern "C" void kernel_launch(void* const* d_in, const int* in_sizes, int n_in,
                              void* d_out, int out_size, void* d_ws,
                              size_t ws_size, hipStream_t stream) {
  const float* x = (const float*)d_in[0];
  const float* gn_w = (const float*)d_in[1];
  const float* gn_b = (const float*)d_in[2];
  const float* qkv_w = (const float*)d_in[3];
  const float* proj_w = (const float*)d_in[4];
  const float* proj_b = (const float*)d_in[5];
  float* out = (float*)d_out;

  char* ws = (char*)d_ws;
  const size_t MB = 1024 * 1024;
  _Float16* qkw = (_Float16*)(ws);                 // 1 MiB
  _Float16* vw = (_Float16*)(ws + 1 * MB);         // 0.5 MiB
  _Float16* pw = (_Float16*)(ws + 3 * MB / 2);     // 0.5 MiB
  float2* stats = (float2*)(ws + 2 * MB);          // 2 KiB
  _Float16* xnT = (_Float16*)(ws + 3 * MB);        // 8 MiB  [b][n][512]
  _Float16* qkT = (_Float16*)(ws + 11 * MB);       // 16 MiB [b][n][1024]
  _Float16* vT = (_Float16*)(ws + 27 * MB);        // 8 MiB  [b][vr][n]
  _Float16* hT = (_Float16*)(ws + 35 * MB);        // 8 MiB  [b][n][512]

  prep<<<dim3(768), 256, 0, stream>>>(qkv_w, proj_w, x, qkw, vw, pw, stats);
  gn_norm<<<dim3(64, B_), 256, 0, stream>>>(x, gn_w, gn_b, stats, xnT);
  gemm_tn<true, false><<<dim3(8, 8, B_), 256, 0, stream>>>(
      xnT, (long)N_ * C_, qkw, 0L, qkT, (long)N_ * 1024, 1024, C_,
      nullptr, nullptr, 0L);
  gemm_tn<true, false><<<dim3(8, 4, B_), 256, 0, stream>>>(
      vw, 0L, xnT, (long)N_ * C_, vT, (long)512 * 1024, 1024, C_,
      nullptr, nullptr, 0L);
  attn_mfma<<<dim3(N_ / 128, B_ * NH_), 256, 0, stream>>>(qkT, vT, hT);
  gemm_tn<false, true><<<dim3(8, 4, B_), 256, 0, stream>>>(
      pw, 0L, hT, (long)N_ * C_, out, (long)C_ * N_, N_, C_,
      proj_b, x, (long)C_ * N_);
}

// Round 5
// 168.768 us; speedup vs baseline: 3.5916x; 1.0137x over previous
//
#include <hip/hip_runtime.h>

#define B_ 8
#define C_ 512
#define N_ 1024
#define GROUPS_ 32
#define CPG_ 16
#define NH_ 8
#define HD_ 64

typedef _Float16 half8 __attribute__((ext_vector_type(8)));
typedef _Float16 half2v __attribute__((ext_vector_type(2)));
typedef float f32x4 __attribute__((ext_vector_type(4)));
typedef float f32x16 __attribute__((ext_vector_type(16)));

// 0.125 (qk softmax scale) * log2(e): folded into Q weights -> exp2-domain softmax
#define QSCALE 0.18033688011112042f
#define THR_LOG2 11.0f

// async global->LDS, 16B per lane; LDS dest is wave-uniform base + lane*16
__device__ __forceinline__ void gload_lds16(const void* g, void* l) {
  __builtin_amdgcn_global_load_lds(
      (const __attribute__((address_space(1))) unsigned int*)g,
      (__attribute__((address_space(3))) unsigned int*)l, 16, 0, 0);
}

// ---------------------------------------------------------------------------
// prep: blocks 0..511 pack weights fp32->fp16 (reordered);
//       blocks 512..767 compute GroupNorm stats.
// ---------------------------------------------------------------------------
__global__ __launch_bounds__(256) void prep(
    const float* __restrict__ qkv_w, const float* __restrict__ proj_w,
    const float* __restrict__ x, _Float16* __restrict__ qkw,
    _Float16* __restrict__ vw, _Float16* __restrict__ pw,
    float2* __restrict__ stats) {
  const int tid = threadIdx.x;
  if (blockIdx.x < 512) {
    const int R = blockIdx.x * 4 + (tid >> 6);
    const int k = (tid & 63) * 8;
    const float* src;
    _Float16* dst;
    float sc = 1.f;
    if (R < 1024) {
      const int head = R >> 7, r = R & 127;
      src = qkv_w + (size_t)(head * 192 + r) * 512;
      if (r < 64) sc = QSCALE;
      dst = qkw + (size_t)R * 512;
    } else if (R < 1536) {
      const int vr = R - 1024;
      const int head = vr >> 6, c = vr & 63;
      src = qkv_w + (size_t)(head * 192 + 128 + c) * 512;
      dst = vw + (size_t)vr * 512;
    } else {
      src = proj_w + (size_t)(R - 1536) * 512;
      dst = pw + (size_t)(R - 1536) * 512;
    }
    const float4 v0 = *reinterpret_cast<const float4*>(src + k);
    const float4 v1 = *reinterpret_cast<const float4*>(src + k + 4);
    _Float16 h[8] = {(_Float16)(v0.x * sc), (_Float16)(v0.y * sc),
                     (_Float16)(v0.z * sc), (_Float16)(v0.w * sc),
                     (_Float16)(v1.x * sc), (_Float16)(v1.y * sc),
                     (_Float16)(v1.z * sc), (_Float16)(v1.w * sc)};
    *reinterpret_cast<float4*>(dst + k) = *reinterpret_cast<float4*>(h);
  } else {
    const int bg = blockIdx.x - 512;
    const int b = bg / GROUPS_, g = bg % GROUPS_;
    const float* xp = x + ((size_t)b * C_ + (size_t)g * CPG_) * N_;
    const int total = CPG_ * N_;
    float s = 0.f, ss = 0.f;
    for (int i = tid * 4; i < total; i += 1024) {
      const float4 v = *reinterpret_cast<const float4*>(xp + i);
      s += v.x + v.y + v.z + v.w;
      ss += v.x * v.x + v.y * v.y + v.z * v.z + v.w * v.w;
    }
#pragma unroll
    for (int off = 32; off > 0; off >>= 1) {
      s += __shfl_down(s, off);
      ss += __shfl_down(ss, off);
    }
    __shared__ float red[8];
    if ((tid & 63) == 0) { red[tid >> 6] = s; red[4 + (tid >> 6)] = ss; }
    __syncthreads();
    if (tid == 0) {
      s = red[0] + red[1] + red[2] + red[3];
      ss = red[4] + red[5] + red[6] + red[7];
      const float inv = 1.0f / (float)total;
      const float mu = s * inv;
      const float var = ss * inv - mu * mu;
      stats[bg] = make_float2(mu, rsqrtf(var + 1e-5f));
    }
  }
}

// ---------------------------------------------------------------------------
// GroupNorm normalize + transpose to xnT[b][n][c] fp16 (1KB coalesced rows).
// ---------------------------------------------------------------------------
__global__ __launch_bounds__(256) void gn_norm(const float* __restrict__ x,
                                               const float* __restrict__ gw,
                                               const float* __restrict__ gb,
                                               const float2* __restrict__ stats,
                                               _Float16* __restrict__ xnT) {
  const int n0 = blockIdx.x * 16;
  const int b = blockIdx.y;
  __shared__ _Float16 T[16][520];
  __shared__ float wsh[512], bsh[512];
  const int tid = threadIdx.x;
  for (int c = tid; c < 512; c += 256) {
    const float2 st = stats[b * 32 + (c >> 4)];
    const float wv = gw[c] * st.y;
    wsh[c] = wv;
    bsh[c] = gb[c] - st.x * wv;
  }
  __syncthreads();
  {
    const int n = tid & 15;
    const int cb = tid >> 4;
    const float* xb = x + (size_t)b * C_ * N_ + n0 + n;
#pragma unroll
    for (int i = 0; i < 32; ++i) {
      const int c = i * 16 + cb;
      T[n][c] = (_Float16)(xb[(size_t)c * N_] * wsh[c] + bsh[c]);
    }
  }
  __syncthreads();
  const int row = tid >> 4;
  const int seg = tid & 15;
  _Float16* dst = &xnT[((size_t)b * N_ + n0 + row) * C_ + seg * 32];
  const _Float16* srcp = &T[row][seg * 32];
  *reinterpret_cast<float4*>(dst) = *reinterpret_cast<const float4*>(srcp);
  *reinterpret_cast<float4*>(dst + 8) = *reinterpret_cast<const float4*>(srcp + 8);
  *reinterpret_cast<float4*>(dst + 16) = *reinterpret_cast<const float4*>(srcp + 16);
  *reinterpret_cast<float4*>(dst + 24) = *reinterpret_cast<const float4*>(srcp + 24);
}

// ---------------------------------------------------------------------------
// Merged QK + V GEMM (one launch, 768 blocks):
//  y<8 : qkT[b][n][ch] = sum_k xnT[b][n][k] * qkw[ch][k]   (ar=n, bc=ch)
//  y>=8: vT[b][vr][n]  = sum_k vw[vr][k]   * xnT[b][n][k]  (ar=vr, bc=n)
// 128x128 tile, BK=64, dbuf LDS via global_load_lds, XOR-swizzled granules.
// ---------------------------------------------------------------------------
__global__ __launch_bounds__(256, 2) void gemm_qkv(
    const _Float16* __restrict__ xnT, const _Float16* __restrict__ qkw,
    const _Float16* __restrict__ vw, _Float16* __restrict__ qkT,
    _Float16* __restrict__ vT) {
  const int b = blockIdx.z;
  const int bc0 = blockIdx.x * 128;
  int ar0;
  const _Float16 *Ab, *Bb;
  _Float16* Dp;
  if (blockIdx.y < 8) {
    ar0 = blockIdx.y * 128;
    Ab = xnT + (size_t)b * N_ * C_;
    Bb = qkw;
    Dp = qkT + (size_t)b * N_ * 1024;
  } else {
    ar0 = (blockIdx.y - 8) * 128;
    Ab = vw;
    Bb = xnT + (size_t)b * N_ * C_;
    Dp = vT + (size_t)b * 512 * 1024;
  }
  const int K = 512;

  __shared__ _Float16 As[2][128][64];
  __shared__ _Float16 Bs[2][128][64];

  const int tid = threadIdx.x;
  const int lane = tid & 63;
  const int wid = tid >> 6;
  const int war = (wid >> 1) * 64;
  const int wbc = (wid & 1) * 64;
  const int lg = lane >> 4;
  const int lr = lane & 15;

  const int srow = lane >> 3;
  const int sgr = (lane & 7) ^ srow;

#define STAGE(buf, koff)                                                     \
  _Pragma("unroll") for (int i = 0; i < 4; ++i) {                            \
    const int rb = (i * 4 + wid) * 8;                                        \
    gload_lds16(&Ab[(size_t)(ar0 + rb + srow) * K + (koff) + sgr * 8],       \
                &As[buf][rb][0]);                                            \
    gload_lds16(&Bb[(size_t)(bc0 + rb + srow) * K + (koff) + sgr * 8],       \
                &Bs[buf][rb][0]);                                            \
  }

  f32x4 acc[4][4] = {};

  STAGE(0, 0)
  __syncthreads();

  int cur = 0;
#pragma unroll 1
  for (int step = 0; step < 8; ++step) {
    if (step + 1 < 8) { STAGE(cur ^ 1, (step + 1) << 6) }
    const half8* Ah = reinterpret_cast<const half8*>(&As[cur][0][0]);
    const half8* Bh = reinterpret_cast<const half8*>(&Bs[cur][0][0]);
#pragma unroll
    for (int kc = 0; kc < 2; ++kc) {
      half8 af[4], bf[4];
#pragma unroll
      for (int i = 0; i < 4; ++i)
        af[i] = Ah[(war + i * 16 + lr) * 8 + ((4 * kc + lg) ^ (lr & 7))];
#pragma unroll
      for (int j = 0; j < 4; ++j)
        bf[j] = Bh[(wbc + j * 16 + lr) * 8 + ((4 * kc + lg) ^ (lr & 7))];
#pragma unroll
      for (int i = 0; i < 4; ++i)
#pragma unroll
        for (int j = 0; j < 4; ++j)
          acc[i][j] = __builtin_amdgcn_mfma_f32_16x16x32_f16(af[i], bf[j],
                                                             acc[i][j], 0, 0, 0);
    }
    __syncthreads();
    cur ^= 1;
  }
#undef STAGE

#pragma unroll
  for (int i = 0; i < 4; ++i)
#pragma unroll
    for (int r = 0; r < 4; ++r) {
      const int row = ar0 + war + i * 16 + lg * 4 + r;
#pragma unroll
      for (int j = 0; j < 4; ++j) {
        const int col = bc0 + wbc + j * 16 + lr;
        Dp[(size_t)row * 1024 + col] = (_Float16)acc[i][j][r];
      }
    }
}

// ---------------------------------------------------------------------------
// Proj GEMM: out[b][c][n] = sum_k pw[c][k]*hT[b][n][k] + proj_b[c] + x[b][c][n]
// 128(M=c) x 64(N=n) tile, BK=64 dbuf, 512 blocks (2/CU).
// 4 waves as 2x2, wave tile 64x32.
// ---------------------------------------------------------------------------
__global__ __launch_bounds__(256, 2) void gemm_proj(
    const _Float16* __restrict__ pw, const _Float16* __restrict__ hT,
    float* __restrict__ out, const float* __restrict__ bias,
    const float* __restrict__ resid) {
  const int bc0 = blockIdx.x * 64;   // n
  const int ar0 = blockIdx.y * 128;  // c
  const int b = blockIdx.z;
  const _Float16* Bb = hT + (size_t)b * N_ * C_;
  const int K = 512;

  __shared__ _Float16 As[2][128][64];
  __shared__ _Float16 Bs[2][64][64];

  const int tid = threadIdx.x;
  const int lane = tid & 63;
  const int wid = tid >> 6;
  const int war = (wid >> 1) * 64;
  const int wbc = (wid & 1) * 32;
  const int lg = lane >> 4;
  const int lr = lane & 15;

  const int srow = lane >> 3;
  const int sgr = (lane & 7) ^ srow;

#define STAGEP(buf, koff)                                                    \
  _Pragma("unroll") for (int i = 0; i < 4; ++i) {                            \
    const int rb = (i * 4 + wid) * 8;                                        \
    gload_lds16(&pw[(size_t)(ar0 + rb + srow) * K + (koff) + sgr * 8],       \
                &As[buf][rb][0]);                                            \
  }                                                                          \
  _Pragma("unroll") for (int i = 0; i < 2; ++i) {                            \
    const int rb = (i * 4 + wid) * 8;                                        \
    gload_lds16(&Bb[(size_t)(bc0 + rb + srow) * K + (koff) + sgr * 8],       \
                &Bs[buf][rb][0]);                                            \
  }

  f32x4 acc[4][2] = {};

  STAGEP(0, 0)
  __syncthreads();

  int cur = 0;
#pragma unroll 1
  for (int step = 0; step < 8; ++step) {
    if (step + 1 < 8) { STAGEP(cur ^ 1, (step + 1) << 6) }
    const half8* Ah = reinterpret_cast<const half8*>(&As[cur][0][0]);
    const half8* Bh = reinterpret_cast<const half8*>(&Bs[cur][0][0]);
#pragma unroll
    for (int kc = 0; kc < 2; ++kc) {
      half8 af[4], bf[2];
#pragma unroll
      for (int i = 0; i < 4; ++i)
        af[i] = Ah[(war + i * 16 + lr) * 8 + ((4 * kc + lg) ^ (lr & 7))];
#pragma unroll
      for (int j = 0; j < 2; ++j)
        bf[j] = Bh[(wbc + j * 16 + lr) * 8 + ((4 * kc + lg) ^ (lr & 7))];
#pragma unroll
      for (int i = 0; i < 4; ++i)
#pragma unroll
        for (int j = 0; j < 2; ++j)
          acc[i][j] = __builtin_amdgcn_mfma_f32_16x16x32_f16(af[i], bf[j],
                                                             acc[i][j], 0, 0, 0);
    }
    __syncthreads();
    cur ^= 1;
  }
#undef STAGEP

  float* Dp = out + (size_t)b * C_ * N_;
  const float* Rp = resid + (size_t)b * C_ * N_;
#pragma unroll
  for (int i = 0; i < 4; ++i)
#pragma unroll
    for (int r = 0; r < 4; ++r) {
      const int row = ar0 + war + i * 16 + lg * 4 + r;
      const float bv = bias[row];
#pragma unroll
      for (int j = 0; j < 2; ++j) {
        const int col = bc0 + wbc + j * 16 + lr;
        const size_t off = (size_t)row * N_ + col;
        Dp[off] = acc[i][j][r] + bv + Rp[off];
      }
    }
}

// ---------------------------------------------------------------------------
// Flash attention, 32x32x16 MFMA, swapped QK^T, in-register P.
// K/V double-buffered in LDS via global_load_lds with XOR-swizzled granules;
// ONE barrier per tile; stage issued before compute (2-phase).
// ---------------------------------------------------------------------------
__global__ __launch_bounds__(256, 2) void attn_mfma(
    const _Float16* __restrict__ qkT, const _Float16* __restrict__ vT,
    _Float16* __restrict__ hT) {
  const int qb = blockIdx.x * 128;
  const int bh = blockIdx.y;
  const int b = bh >> 3, head = bh & 7;
  const int tid = threadIdx.x;
  const int lane = tid & 63;
  const int w = tid >> 6;
  const int l31 = lane & 31;
  const int lg2 = lane >> 5;

  __shared__ _Float16 Ks[2][64][64];  // [s][c], swizzled granules
  __shared__ _Float16 Vs[2][64][64];  // [c][s], swizzled granules

  const size_t qkbase = (size_t)b * N_ * 1024;

  // Q fragments in registers (pre-scaled by QSCALE at weight pack)
  half8 bfq[4];
#pragma unroll
  for (int kc = 0; kc < 4; ++kc)
    bfq[kc] = *reinterpret_cast<const half8*>(
        &qkT[qkbase + (size_t)(qb + w * 32 + l31) * 1024 + head * 128 +
             kc * 16 + lg2 * 8]);

  // staging mapping: wave w stages rows w*16..w*16+15 (2 gloads of 8 rows)
  const int srow = lane >> 3;                    // 0..7
  const int sgrh = ((lane & 7) ^ srow) * 8;      // swizzled granule (halves)
  const int r0 = w * 16 + srow;
  const _Float16* kp = qkT + qkbase + head * 128 + 64 + sgrh;  // +(sb+row)*1024
  const _Float16* vp = vT + (size_t)bh * 64 * 1024 + sgrh;     // +row*1024+sb

#define STAGEA(buf, sb)                                                      \
  gload_lds16(kp + (size_t)((sb) + r0) * 1024, &Ks[buf][w * 16][0]);         \
  gload_lds16(kp + (size_t)((sb) + r0 + 8) * 1024, &Ks[buf][w * 16 + 8][0]); \
  gload_lds16(vp + (size_t)r0 * 1024 + (sb), &Vs[buf][w * 16][0]);           \
  gload_lds16(vp + (size_t)(r0 + 8) * 1024 + (sb), &Vs[buf][w * 16 + 8][0]);

  f32x16 oacc[2];
#pragma unroll
  for (int ct = 0; ct < 2; ++ct)
#pragma unroll
    for (int r = 0; r < 16; ++r) oacc[ct][r] = 0.f;
  float m_run = -1e30f, l_run = 0.f;

  STAGEA(0, 0)
  __syncthreads();

  int cur = 0;
#pragma unroll 1
  for (int t = 0; t < 16; ++t) {
    if (t < 15) { STAGEA(cur ^ 1, (t + 1) * 64) }

    // S^T = K·Q (one query column per lane)
    f32x16 sacc[2];
#pragma unroll
    for (int st = 0; st < 2; ++st)
#pragma unroll
      for (int r = 0; r < 16; ++r) sacc[st][r] = 0.f;
    __builtin_amdgcn_s_setprio(1);
#pragma unroll
    for (int st = 0; st < 2; ++st)
#pragma unroll
      for (int kc = 0; kc < 4; ++kc) {
        const half8 af = *reinterpret_cast<const half8*>(
            &Ks[cur][st * 32 + l31][((kc * 2 + lg2) ^ (l31 & 7)) * 8]);
        sacc[st] = __builtin_amdgcn_mfma_f32_32x32x16_f16(af, bfq[kc],
                                                          sacc[st], 0, 0, 0);
      }
    __builtin_amdgcn_s_setprio(0);

    // online softmax (exp2 domain), defer-max
    float mt = -1e30f;
#pragma unroll
    for (int st = 0; st < 2; ++st)
#pragma unroll
      for (int r = 0; r < 16; ++r) mt = fmaxf(mt, sacc[st][r]);
    mt = fmaxf(mt, __shfl_xor(mt, 32));
    if (!__all(mt <= m_run + THR_LOG2)) {
      const float mn = fmaxf(m_run, mt);
      const float alpha = exp2f(m_run - mn);
      m_run = mn;
      l_run *= alpha;
#pragma unroll
      for (int r = 0; r < 16; ++r) {
        const int qrow = (r & 3) + 8 * (r >> 2) + 4 * lg2;
        const float ar = __shfl(alpha, qrow);
        oacc[0][r] *= ar;
        oacc[1][r] *= ar;
      }
    }
    const float mr = m_run;
    float ps = 0.f;
#pragma unroll
    for (int st = 0; st < 2; ++st)
#pragma unroll
      for (int r = 0; r < 16; ++r) {
        const float p = exp2f(sacc[st][r] - mr);
        sacc[st][r] = p;
        ps += p;
      }
    ps += __shfl_xor(ps, 32);
    l_run += ps;

    // pack P -> PV A-fragments (cross-half exchange via shfl_xor 32)
    half8 pa[4];
    {
      unsigned int wo[2][8];
#pragma unroll
      for (int st = 0; st < 2; ++st)
#pragma unroll
        for (int m = 0; m < 8; ++m) {
          union { half2v h; unsigned int u; } cv;
          cv.h.x = (_Float16)sacc[st][2 * m];
          cv.h.y = (_Float16)sacc[st][2 * m + 1];
          wo[st][m] = cv.u;
        }
#pragma unroll
      for (int kc = 0; kc < 4; ++kc) {
        const int st = kc >> 1;
        const int base = 4 * (kc & 1);
        const unsigned int a0 = wo[st][base], a1 = wo[st][base + 1];
        const unsigned int a2 = wo[st][base + 2], a3 = wo[st][base + 3];
        const unsigned int x0 = __shfl_xor(a0, 32);
        const unsigned int x1 = __shfl_xor(a1, 32);
        const unsigned int x2 = __shfl_xor(a2, 32);
        const unsigned int x3 = __shfl_xor(a3, 32);
        union { unsigned int u[4]; half8 h; } fr;
        fr.u[0] = lg2 ? x2 : a0;
        fr.u[1] = lg2 ? x3 : a1;
        fr.u[2] = lg2 ? a2 : x0;
        fr.u[3] = lg2 ? a3 : x1;
        pa[kc] = fr.h;
      }
    }

    // O += P·V
    __builtin_amdgcn_s_setprio(1);
#pragma unroll
    for (int ct = 0; ct < 2; ++ct)
#pragma unroll
      for (int ks = 0; ks < 4; ++ks) {
        const half8 vf = *reinterpret_cast<const half8*>(
            &Vs[cur][ct * 32 + l31][((ks * 2 + lg2) ^ (l31 & 7)) * 8]);
        oacc[ct] = __builtin_amdgcn_mfma_f32_32x32x16_f16(pa[ks], vf,
                                                          oacc[ct], 0, 0, 0);
      }
    __builtin_amdgcn_s_setprio(0);

    __syncthreads();  // drains vmcnt (next buf staged) + all LDS reads done
    cur ^= 1;
  }
#undef STAGEA

  const size_t hbase = ((size_t)b * N_ + qb) * C_ + head * 64;
  const float linv = 1.f / l_run;
#pragma unroll
  for (int r = 0; r < 16; ++r) {
    const int qrow = (r & 3) + 8 * (r >> 2) + 4 * lg2;
    const float li = __shfl(linv, qrow);
    const size_t rowoff = hbase + (size_t)(w * 32 + qrow) * C_;
#pragma unroll
    for (int ct = 0; ct < 2; ++ct)
      hT[rowoff + ct * 32 + l31] = (_Float16)(oacc[ct][r] * li);
  }
}

// ---------------------------------------------------------------------------
extern "C" void kernel_launch(void* const* d_in, const int* in_sizes, int n_in,
                              void* d_out, int out_size, void* d_ws,
                              size_t ws_size, hipStream_t stream) {
  const float* x = (const float*)d_in[0];
  const float* gn_w = (const float*)d_in[1];
  const float* gn_b = (const float*)d_in[2];
  const float* qkv_w = (const float*)d_in[3];
  const float* proj_w = (const float*)d_in[4];
  const float* proj_b = (const float*)d_in[5];
  float* out = (float*)d_out;

  char* ws = (char*)d_ws;
  const size_t MB = 1024 * 1024;
  _Float16* qkw = (_Float16*)(ws);                 // 1 MiB
  _Float16* vw = (_Float16*)(ws + 1 * MB);         // 0.5 MiB
  _Float16* pw = (_Float16*)(ws + 3 * MB / 2);     // 0.5 MiB
  float2* stats = (float2*)(ws + 2 * MB);          // 2 KiB
  _Float16* xnT = (_Float16*)(ws + 3 * MB);        // 8 MiB  [b][n][512]
  _Float16* qkT = (_Float16*)(ws + 11 * MB);       // 16 MiB [b][n][1024]
  _Float16* vT = (_Float16*)(ws + 27 * MB);        // 8 MiB  [b][vr][n]
  _Float16* hT = (_Float16*)(ws + 35 * MB);        // 8 MiB  [b][n][512]

  prep<<<dim3(768), 256, 0, stream>>>(qkv_w, proj_w, x, qkw, vw, pw, stats);
  gn_norm<<<dim3(64, B_), 256, 0, stream>>>(x, gn_w, gn_b, stats, xnT);
  gemm_qkv<<<dim3(8, 12, B_), 256, 0, stream>>>(xnT, qkw, vw, qkT, vT);
  attn_mfma<<<dim3(N_ / 128, B_ * NH_), 256, 0, stream>>>(qkT, vT, hT);
  gemm_proj<<<dim3(16, 4, B_), 256, 0, stream>>>(pw, hT, out, proj_b, x);
}